// Round 5
// baseline (187.922 us; speedup 1.0000x reference)
//
#include <hip/hip_runtime.h>

// PWC-Net correlation: out[b, dy*9+dx, y, x] =
//   (1/C) * sum_c first[b,c,y,x] * second[b,c, y+dy-4, x+dx-4]  (zero-padded)
// B=8, C=128, H=W=128.
//
// Round 10: DMA *concurrency* theory. R0 proved the DMA path does >=15B/cyc/CU
// with ~120KB in flight; R3/R4 run depth-1 (20KB/block in flight) and land at
// 9.3B/cyc. This round: CC=2 (64 chunks), NBUF=4, stage-at-END schedule with
// ONE barrier per chunk and counted per-wave vmcnt(2N): chunks k+1,k+2(,k+3)
// stay in flight = ~30KB/block = 90KB/CU (R0-level concurrency at R4-level
// bytes). Barrier count unchanged (64) so the delta attributes to depth.
// Also: bank-conflict kill via 16B-unit source swizzle p = v ^ (v>>3) within
// each 512B row (per-lane GLOBAL source swizzled, DMA dest linear, read site
// applies the same involution): 16 lanes/read spread 1-per-bank-quad.
// Pred: conflicts 7.09M -> <1M; dur 86 -> 58-68us (flat ~85 kills theory).

#define B  8
#define C  128
#define H  128
#define W  128
#define CC 2
#define YB 4
#define XT 8
#define NTHR 192
#define NCHUNK (C / CC)        // 64
#define SROWS 6                // second rows per dy-group (yi 0..3 + w 0..2)
#define NBUF 4
#define CHSTRIDE (CC * H * W)  // 32768 floats per chunk step

typedef const void __attribute__((address_space(1)))* gvp;
typedef void __attribute__((address_space(3)))* lvp;

__device__ __forceinline__ void dma16(const float* g, float* l) {
    __builtin_amdgcn_global_load_lds((gvp)g, (lvp)l, 16, 0, 0);
}

// involution on 16B-unit index within a 512B row (v in [0,32))
__device__ __forceinline__ int swz(int v) { return v ^ (v >> 3); }

__global__ __launch_bounds__(NTHR) __attribute__((amdgpu_waves_per_eu(3)))
void ModuleCorrelation_41970420416706_kernel(const float* __restrict__ first,
                                             const float* __restrict__ second,
                                             float* __restrict__ out) {
    __shared__ __align__(16) float sFirst[NBUF][CC][YB * W];    // 16 KiB
    __shared__ __align__(16) float sSec[NBUF][CC][SROWS * W];   // 24 KiB

    // ---- XCD swizzle: phys blocks round-robin XCDs; XCD k gets batch b=k ----
    const int phys = blockIdx.x;
    const int li   = (phys & 7) * 96 + (phys >> 3);   // 768 = 8*96, bijective
    const int b    = li / 96;
    const int rem  = li - b * 96;
    const int y0   = (rem / 3) * YB;
    const int dg   = rem - (rem / 3) * 3;    // dg fastest: siblings adjacent
    const int d0   = dg * 3;                 // dy group base: 0, 3, 6
    const int base = y0 + d0 - 4;            // global row of sSec rr=0

    const int t    = threadIdx.x;
    const int w    = t >> 6;                 // wave = dy - d0, in [0,3)
    const int lane = t & 63;
    const int yi   = lane >> 4;              // 0..3
    const int xt   = lane & 15;              // 0..15
    const int x0   = xt * XT;                // 0,8,...,120

    const float* firstB  = first  + (size_t)b * C * H * W;
    const float* secondB = second + (size_t)b * C * H * W;

    // per-lane swizzled source term for pair-DMAs (floats):
    // row half (lane>>5) + swizzled 16B unit within the 512B row
    const int srcterm = (lane >> 5) * W + swz(lane & 31) * 4;

    // ---- pair-DMA geometry (block-uniform): pair p covers global rows
    //      g=base+2p,g+1 -> LDS rows 2p,2p+1; clamp g to [0,H-2], shift dest
    //      by the same amount (written rows always correct; OOB never written)
    int gs[3], dr[3];
#pragma unroll
    for (int p = 0; p < 3; ++p) {
        const int g  = base + 2 * p;
        const int gc = g < 0 ? 0 : (g > H - 2 ? H - 2 : g);
        gs[p] = gc;
        dr[p] = gc - base;                   // dest row in [0, 5]
    }

    // ---- staging: 10 full-wave 1KB pair-DMAs per chunk.
    //      w0: first (2 pairs x 2c); w1: second c=0 (3); w2: second c=1 (3) ----
    auto stage = [&](int buf, int chunk) {
        const int off = chunk * CHSTRIDE;
        if (w == 0) {
#pragma unroll
            for (int c = 0; c < CC; ++c)
#pragma unroll
                for (int p = 0; p < 2; ++p)
                    dma16(firstB + off + (c * H + y0 + 2 * p) * W + srcterm,
                          &sFirst[buf][c][p * 2 * W]);
        } else {
            const int c = w - 1;             // wave-uniform
#pragma unroll
            for (int p = 0; p < 3; ++p)
                dma16(secondB + off + (c * H + gs[p]) * W + srcterm,
                      &sSec[buf][c][dr[p] * W]);
        }
    };

    // ---- prologue: stage chunks 0..2; zero never-written OOB rows once ----
    stage(0, 0);
    stage(1, 1);
    stage(2, 2);
    {
        const float4 z4 = make_float4(0.f, 0.f, 0.f, 0.f);
        for (int idx = t; idx < NBUF * CC * SROWS; idx += NTHR) {  // 48 rows
            const int rr = idx % SROWS;
            const int ys = base + rr;
            if (ys < 0 || ys >= H) {
                const int bf = idx / (CC * SROWS);
                const int c  = (idx / SROWS) % CC;
                float4* p4 = (float4*)&sSec[bf][c][rr * W];
                for (int x = 0; x < W / 4; ++x) p4[x] = z4;
            }
        }
    }
    asm volatile("s_waitcnt lgkmcnt(0)" ::: "memory");   // zero-stores done

    float acc[9][XT];
#pragma unroll
    for (int dx = 0; dx < 9; ++dx)
#pragma unroll
        for (int j = 0; j < XT; ++j) acc[dx][j] = 0.f;

    // ---- per-thread swizzled read offsets (floats, within a row) ----
    const bool edgeL = (xt == 0);
    const bool edgeR = (xt == 15);
    const int va = edgeL ? 0 : 2 * xt - 1;
    const int vb = 2 * xt;
    const int vc = 2 * xt + 1;
    const int vd = edgeR ? 31 : 2 * xt + 2;
    const int pa = swz(va) * 4, pb = swz(vb) * 4, pc = swz(vc) * 4,
              pd = swz(vd) * 4;
    const int fRow = yi * W;
    const int sRow = (yi + w) * W;           // rr = yi + w

    for (int k = 0; k < NCHUNK; ++k) {
        const int buf = k & (NBUF - 1);
        // 1) wait for OWN chunk-k DMAs: issued through chunk min(k+2, last);
        //    allowed outstanding = chunks beyond k = min(2, 63-k) x N_wave.
        const int m2 = NCHUNK - 1 - k;
        if (m2 >= 2) {
            if (w == 0) asm volatile("s_waitcnt vmcnt(8)" ::: "memory");
            else        asm volatile("s_waitcnt vmcnt(6)" ::: "memory");
        } else if (m2 == 1) {
            if (w == 0) asm volatile("s_waitcnt vmcnt(4)" ::: "memory");
            else        asm volatile("s_waitcnt vmcnt(3)" ::: "memory");
        } else {
            asm volatile("s_waitcnt vmcnt(0)" ::: "memory");
        }
        asm volatile("s_waitcnt lgkmcnt(0)" ::: "memory");
        // 2) publish chunk k; also proves buf (k-1)%4 fully consumed
        asm volatile("s_barrier" ::: "memory");

        // 3) compute chunk k
        const float* sF  = &sFirst[buf][0][0];
        const float* sSb = &sSec[buf][0][0];
#pragma unroll
        for (int c = 0; c < CC; ++c) {
            const float* fr = sF + c * (YB * W) + fRow;
            const float4 f0 = *(const float4*)(fr + pb);
            const float4 f1 = *(const float4*)(fr + pc);
            const float* sr = sSb + c * (SROWS * W) + sRow;
            float4 A        = *(const float4*)(sr + pa);
            const float4 B0 = *(const float4*)(sr + pb);
            const float4 B1 = *(const float4*)(sr + pc);
            float4 Cv       = *(const float4*)(sr + pd);
            if (edgeL) { A.x = 0.f; A.y = 0.f; A.z = 0.f; A.w = 0.f; }
            if (edgeR) { Cv.x = 0.f; Cv.y = 0.f; Cv.z = 0.f; Cv.w = 0.f; }
            const float s[16] = {A.x,  A.y,  A.z,  A.w,
                                 B0.x, B0.y, B0.z, B0.w,
                                 B1.x, B1.y, B1.z, B1.w,
                                 Cv.x, Cv.y, Cv.z, Cv.w};
            const float ff[8] = {f0.x, f0.y, f0.z, f0.w,
                                 f1.x, f1.y, f1.z, f1.w};
#pragma unroll
            for (int dx = 0; dx < 9; ++dx)
#pragma unroll
                for (int j = 0; j < XT; ++j)
                    acc[dx][j] += ff[j] * s[dx + j];
        }

        // 4) stage chunk k+3 into buf (k+3)%4 (= (k-1)%4, freed by barrier)
        if (k + 3 < NCHUNK) stage((k + 3) & (NBUF - 1), k + 3);
    }

    // ---- epilogue ----
    const float scale = 1.0f / (float)C;
    const int dy = d0 + w;
    const int yOut = y0 + yi;
#pragma unroll
    for (int dx = 0; dx < 9; ++dx) {
        const int tc = dy * 9 + dx;
        float* op = &out[((b * 81 + tc) * H + yOut) * W + x0];
        float4 o0, o1;
        o0.x = acc[dx][0] * scale;
        o0.y = acc[dx][1] * scale;
        o0.z = acc[dx][2] * scale;
        o0.w = acc[dx][3] * scale;
        o1.x = acc[dx][4] * scale;
        o1.y = acc[dx][5] * scale;
        o1.z = acc[dx][6] * scale;
        o1.w = acc[dx][7] * scale;
        *(float4*)op       = o0;
        *(float4*)(op + 4) = o1;
    }
}

extern "C" void kernel_launch(void* const* d_in, const int* in_sizes, int n_in,
                              void* d_out, int out_size, void* d_ws, size_t ws_size,
                              hipStream_t stream) {
    const float* first  = (const float*)d_in[0];
    const float* second = (const float*)d_in[1];
    float* out = (float*)d_out;

    dim3 grid(B * (H / YB) * 3);   // 768 blocks = 8 XCDs x 96 = 3 per CU
    dim3 block(NTHR);              // 192 threads = 3 waves
    ModuleCorrelation_41970420416706_kernel<<<grid, block, 0, stream>>>(first, second, out);
}